// Round 5
// baseline (366.285 us; speedup 1.0000x reference)
//
#include <hip/hip_runtime.h>
#include <hip/hip_bf16.h>
#include <stdint.h>

// B=4, T=4096, K=256, D=1024, H=16, hd=64
#define D_DIM 1024

using f32x4  = __attribute__((ext_vector_type(4))) float;
using short8 = __attribute__((ext_vector_type(8))) short;

__device__ __forceinline__ float bf2f(unsigned short u) {
    union { unsigned int i; float f; } v; v.i = ((unsigned int)u) << 16; return v.f;
}
__device__ __forceinline__ unsigned short f2bf(float f) {
    union { float f; unsigned int i; } v; v.f = f;
    unsigned int x = v.i;
    return (unsigned short)((x + 0x7fffu + ((x >> 16) & 1u)) >> 16);  // RNE
}
__device__ __forceinline__ void gload16(const void* g, void* l) {
    __builtin_amdgcn_global_load_lds(
        (const __attribute__((address_space(1))) void*)g,
        (__attribute__((address_space(3))) void*)l, 16, 0, 0);
}

// LDS tile layout: [row][32 bf16] = 64B rows, 4 x 16B slots per row.
// XOR swizzle (T2, rule #21): LDS dest linear; global source k-seg and the
// ds_read slot are both XORed with (row>>1)&3 (involution). Since all frag
// row offsets are multiples of 16, (row>>1)&3 == (fr>>1)&3.

// ---------------------------------------------------------------------------
// Weight fold+split: W' = gamma ⊙ W, split f32 -> hi+lo bf16.
// sel 0..2 (Wq,Wk,Wv): hi at ws+sel*4MB, lo at +2MB.  sel 3 (Wo): bf16 @12MB.
// ---------------------------------------------------------------------------
__global__ __launch_bounds__(256)
void convw_kernel(const float* __restrict__ Wq, const float* __restrict__ Wk,
                  const float* __restrict__ Wv, const float* __restrict__ Wo,
                  const float* __restrict__ gq, const float* __restrict__ gkv,
                  char* __restrict__ ws)
{
    const int e   = (blockIdx.x * 256 + threadIdx.x) * 4;
    const int sel = e >> 20;
    const int off = e & 0xFFFFF;
    const float* src = sel == 0 ? Wq : sel == 1 ? Wk : sel == 2 ? Wv : Wo;
    float4 v = *(const float4*)(src + off);
    if (sel < 3) {
        const float* gam = (sel == 0) ? gq : gkv;
        float4 g = *(const float4*)(gam + (off & 1023));
        v.x *= g.x; v.y *= g.y; v.z *= g.z; v.w *= g.w;
        ushort4 h, l;
        h.x = f2bf(v.x); l.x = f2bf(v.x - bf2f(h.x));
        h.y = f2bf(v.y); l.y = f2bf(v.y - bf2f(h.y));
        h.z = f2bf(v.z); l.z = f2bf(v.z - bf2f(h.z));
        h.w = f2bf(v.w); l.w = f2bf(v.w - bf2f(h.w));
        unsigned short* hi = (unsigned short*)(ws + (size_t)sel * (4u << 20));
        unsigned short* lo = (unsigned short*)(ws + (size_t)sel * (4u << 20) + (2u << 20));
        *(ushort4*)(hi + off) = h;
        *(ushort4*)(lo + off) = l;
    } else {
        ushort4 o;
        o.x = f2bf(v.x); o.y = f2bf(v.y); o.z = f2bf(v.z); o.w = f2bf(v.w);
        *(ushort4*)((unsigned short*)(ws + (12u << 20)) + off) = o;
    }
}

// ---------------------------------------------------------------------------
// RMSNorm + split: xh = bf16(x*scale), xl = bf16(x*scale - xh). One block/row.
// ---------------------------------------------------------------------------
__global__ __launch_bounds__(256)
void rms_split_kernel(const float* __restrict__ x,
                      unsigned short* __restrict__ xh, unsigned short* __restrict__ xl)
{
    const long row = blockIdx.x;
    float4 v = ((const float4*)(x + row * D_DIM))[threadIdx.x];
    float ss = v.x*v.x + v.y*v.y + v.z*v.z + v.w*v.w;
#pragma unroll
    for (int m = 32; m; m >>= 1) ss += __shfl_xor(ss, m);
    __shared__ float red[4];
    if ((threadIdx.x & 63) == 0) red[threadIdx.x >> 6] = ss;
    __syncthreads();
    const float tot = red[0] + red[1] + red[2] + red[3];
    const float scale = rsqrtf(tot * (1.0f / 1024.0f) + 1.1920929e-07f);
    v.x *= scale; v.y *= scale; v.z *= scale; v.w *= scale;
    ushort4 h, l;
    h.x = f2bf(v.x); l.x = f2bf(v.x - bf2f(h.x));
    h.y = f2bf(v.y); l.y = f2bf(v.y - bf2f(h.y));
    h.z = f2bf(v.z); l.z = f2bf(v.z - bf2f(h.z));
    h.w = f2bf(v.w); l.w = f2bf(v.w - bf2f(h.w));
    *(ushort4*)(xh + row * D_DIM + threadIdx.x * 4) = h;
    *(ushort4*)(xl + row * D_DIM + threadIdx.x * 4) = l;
}

// ---------------------------------------------------------------------------
// kv GEMM: O = (ch+cl) @ (Bhi+Blo)^T, 128x128 tile, 256 thr, pure gload16,
// swizzled LDS. grid (8,8,2): z selects (Wk->k_f) / (Wv->v_f).
// ---------------------------------------------------------------------------
__global__ __launch_bounds__(256)
void gemm_kv(const unsigned short* __restrict__ ch, const unsigned short* __restrict__ cl,
             const unsigned short* __restrict__ Bh0, const unsigned short* __restrict__ Bl0,
             const unsigned short* __restrict__ Bh1, const unsigned short* __restrict__ Bl1,
             float* __restrict__ O0, float* __restrict__ O1)
{
    __shared__ unsigned short Ah[4096], Al[4096], Bh[4096], Bl[4096];  // 8KB each
    const unsigned short* Bhp = blockIdx.z ? Bh1 : Bh0;
    const unsigned short* Blp = blockIdx.z ? Bl1 : Bl0;
    float* O = blockIdx.z ? O1 : O0;

    const int tid = threadIdx.x, lane = tid & 63, wave = tid >> 6;
    const int wm = wave >> 1, wn = wave & 1;
    const long Arow0 = (long)blockIdx.y * 128;
    const int  Brow0 = blockIdx.x * 128;
    const int fr = lane & 15, ks = lane >> 4;
    const int ksz = (ks ^ ((fr >> 1) & 3)) << 4;                   // read swizzle (bytes)
    const int kq  = ((tid & 3) ^ ((tid >> 3) & 3)) * 8;            // source swizzle (elems)
    const int srow = tid >> 2;                                     // staging row (slot tid)

    const long a_off0 = (Arow0 + srow) * D_DIM + kq;
    const long a_off1 = (Arow0 + srow + 64) * D_DIM + kq;
    const long b_off0 = (long)(Brow0 + srow) * D_DIM + kq;
    const long b_off1 = (long)(Brow0 + srow + 64) * D_DIM + kq;

    f32x4 acc[4][4] = {};
    char* AhB = (char*)Ah; char* AlB = (char*)Al;
    char* BhB = (char*)Bh; char* BlB = (char*)Bl;

    for (int kt = 0; kt < 32; ++kt) {
        const int k0 = kt * 32;
        gload16(ch + a_off0 + k0, AhB + tid * 16);
        gload16(ch + a_off1 + k0, AhB + 4096 + tid * 16);
        gload16(cl + a_off0 + k0, AlB + tid * 16);
        gload16(cl + a_off1 + k0, AlB + 4096 + tid * 16);
        gload16(Bhp + b_off0 + k0, BhB + tid * 16);
        gload16(Bhp + b_off1 + k0, BhB + 4096 + tid * 16);
        gload16(Blp + b_off0 + k0, BlB + tid * 16);
        gload16(Blp + b_off1 + k0, BlB + 4096 + tid * 16);
        __syncthreads();

        short8 ah[4], al[4], bh[4], bl[4];
#pragma unroll
        for (int mi = 0; mi < 4; ++mi) {
            const int aoff = (wm * 64 + mi * 16 + fr) * 64 + ksz;
            ah[mi] = *(const short8*)(AhB + aoff);
            al[mi] = *(const short8*)(AlB + aoff);
        }
#pragma unroll
        for (int ni = 0; ni < 4; ++ni) {
            const int boff = (wn * 64 + ni * 16 + fr) * 64 + ksz;
            bh[ni] = *(const short8*)(BhB + boff);
            bl[ni] = *(const short8*)(BlB + boff);
        }
#pragma unroll
        for (int mi = 0; mi < 4; ++mi)
#pragma unroll
            for (int ni = 0; ni < 4; ++ni) {
                acc[mi][ni] = __builtin_amdgcn_mfma_f32_16x16x32_bf16(ah[mi], bh[ni], acc[mi][ni], 0, 0, 0);
                acc[mi][ni] = __builtin_amdgcn_mfma_f32_16x16x32_bf16(al[mi], bh[ni], acc[mi][ni], 0, 0, 0);
                acc[mi][ni] = __builtin_amdgcn_mfma_f32_16x16x32_bf16(ah[mi], bl[ni], acc[mi][ni], 0, 0, 0);
            }
        __syncthreads();
    }

    const int c = lane & 15, r0 = (lane >> 4) * 4;
#pragma unroll
    for (int mi = 0; mi < 4; ++mi)
#pragma unroll
        for (int ni = 0; ni < 4; ++ni)
#pragma unroll
            for (int j = 0; j < 4; ++j) {
                const long row = Arow0 + wm * 64 + mi * 16 + r0 + j;
                const int  col = Brow0 + wn * 64 + ni * 16 + c;
                O[row * D_DIM + col] = acc[mi][ni][j];
            }
}

// ---------------------------------------------------------------------------
// FUSED q-projection + band attention. BM=128 x BN=256 (4 heads), grid 512,
// 8 waves (2x4, wave=64x64), single-buffer 48KB LDS -> 2 blocks/CU.
// Pure gload16 staging (xh/xl pre-split), swizzled LDS. acc[4][4].
// ---------------------------------------------------------------------------
__global__ __launch_bounds__(512, 4)
void qattn3_kernel(const unsigned short* __restrict__ xh, const unsigned short* __restrict__ xl,
                   const unsigned short* __restrict__ Wh, const unsigned short* __restrict__ Wl,
                   const float* __restrict__ kf, const float* __restrict__ vf,
                   const int* __restrict__ cidx, unsigned short* __restrict__ ao)
{
    __shared__ unsigned short Ah[4096], Al[4096];   // 8KB each  (128 rows)
    __shared__ unsigned short Bh[8192], Bl[8192];   // 16KB each (256 rows)

    const int lin = blockIdx.x;
    const int bx = (lin >> 3) & 3;
    const int by = ((lin >> 5) << 3) | (lin & 7);
    const int row0 = by * 128;
    const int col0 = bx * 256;
    const int b = row0 >> 12;

    const int tid = threadIdx.x, lane = tid & 63, wave = tid >> 6;
    const int wm = wave >> 2, wn = wave & 3;
    const int fr = lane & 15, ks = lane >> 4;
    const int ksz = (ks ^ ((fr >> 1) & 3)) << 4;
    const int kq  = ((tid & 3) ^ ((tid >> 3) & 3)) * 8;
    const int srow = tid >> 2;   // [0,128)

    const long a_off  = (long)(row0 + srow) * D_DIM + kq;
    const long w_off0 = (long)(col0 + srow) * D_DIM + kq;
    const long w_off1 = (long)(col0 + 128 + srow) * D_DIM + kq;

    f32x4 acc[4][4] = {};
    char* AhB = (char*)Ah; char* AlB = (char*)Al;
    char* BhB = (char*)Bh; char* BlB = (char*)Bl;

    for (int t = 0; t < 32; ++t) {
        const int k0 = t * 32;
        gload16(xh + a_off + k0, AhB + tid * 16);
        gload16(xl + a_off + k0, AlB + tid * 16);
        gload16(Wh + w_off0 + k0, BhB + tid * 16);
        gload16(Wh + w_off1 + k0, BhB + 8192 + tid * 16);
        gload16(Wl + w_off0 + k0, BlB + tid * 16);
        gload16(Wl + w_off1 + k0, BlB + 8192 + tid * 16);
        __syncthreads();

        short8 bh[4], bl[4];
#pragma unroll
        for (int ni = 0; ni < 4; ++ni) {
            const int boff = (wn * 64 + ni * 16 + fr) * 64 + ksz;
            bh[ni] = *(const short8*)(BhB + boff);
            bl[ni] = *(const short8*)(BlB + boff);
        }
#pragma unroll
        for (int mi = 0; mi < 4; ++mi) {
            const int aoff = (wm * 64 + mi * 16 + fr) * 64 + ksz;
            const short8 ah = *(const short8*)(AhB + aoff);
            const short8 al = *(const short8*)(AlB + aoff);
#pragma unroll
            for (int ni = 0; ni < 4; ++ni) {
                acc[mi][ni] = __builtin_amdgcn_mfma_f32_16x16x32_bf16(ah, bh[ni], acc[mi][ni], 0, 0, 0);
                acc[mi][ni] = __builtin_amdgcn_mfma_f32_16x16x32_bf16(al, bh[ni], acc[mi][ni], 0, 0, 0);
                acc[mi][ni] = __builtin_amdgcn_mfma_f32_16x16x32_bf16(ah, bl[ni], acc[mi][ni], 0, 0, 0);
            }
        }
        __syncthreads();
    }

    // ---- in-register band attention (wave owns head wn of this col-group) ----
    const int c = lane & 15, rg = lane >> 4;
    const int hcol = col0 + wn * 64;
    const float* kb = kf + (long)b * 256 * D_DIM + hcol + c;
    const float* vb = vf + (long)b * 256 * D_DIM + hcol + c;
#pragma unroll
    for (int mi = 0; mi < 4; ++mi) {
        float wgt[4][3];
        int   pos[4][3];
#pragma unroll
        for (int j = 0; j < 4; ++j) {
            const int tok = row0 + wm * 64 + mi * 16 + rg * 4 + j;
            const int idx = cidx[tok];
            float wsum = 0.f;
#pragma unroll
            for (int dp = 0; dp < 3; ++dp) {
                const int p = idx + dp - 1;
                const bool valid = (p >= 0) && (p < 256);
                const int pc = valid ? p : 0;
                const float* kr = kb + (long)pc * D_DIM;
                float dot = acc[mi][0][j] * kr[0]  + acc[mi][1][j] * kr[16]
                          + acc[mi][2][j] * kr[32] + acc[mi][3][j] * kr[48];
                dot += __shfl_xor(dot, 1);
                dot += __shfl_xor(dot, 2);
                dot += __shfl_xor(dot, 4);
                dot += __shfl_xor(dot, 8);
                const float s = dot * 0.125f;
                const float w = (valid && s > 0.f) ? s * s : 0.f;
                wsum += w; wgt[j][dp] = w; pos[j][dp] = pc;
            }
            const float inv = 1.0f / fmaxf(wsum, 1e-6f);
            wgt[j][0] *= inv; wgt[j][1] *= inv; wgt[j][2] *= inv;
        }
#pragma unroll
        for (int ni = 0; ni < 4; ++ni)
#pragma unroll
            for (int j = 0; j < 4; ++j) {
                float a = 0.f;
#pragma unroll
                for (int dp = 0; dp < 3; ++dp)
                    a += wgt[j][dp] * vb[(long)pos[j][dp] * D_DIM + ni * 16];
                acc[mi][ni][j] = a;
            }
    }

#pragma unroll
    for (int mi = 0; mi < 4; ++mi)
#pragma unroll
        for (int ni = 0; ni < 4; ++ni)
#pragma unroll
            for (int j = 0; j < 4; ++j) {
                const long tok = row0 + wm * 64 + mi * 16 + rg * 4 + j;
                ao[tok * D_DIM + hcol + ni * 16 + c] = f2bf(acc[mi][ni][j]);
            }
}

// ---------------------------------------------------------------------------
// out = x + ao @ Wo^T, 256x256, double-buffered, swizzled. grid 256.
// ---------------------------------------------------------------------------
__global__ __launch_bounds__(512, 2)
void gemm_out256(const unsigned short* __restrict__ A,
                 const unsigned short* __restrict__ W,
                 float* __restrict__ C, const float* __restrict__ resid)
{
    __shared__ unsigned short As[2][8192];
    __shared__ unsigned short Bs[2][8192];

    const int lin = blockIdx.x;
    const int bx = (lin >> 3) & 3;
    const int by = ((lin >> 5) << 3) | (lin & 7);
    const long row0 = (long)by * 256;
    const int  col0 = bx * 256;

    const int tid = threadIdx.x, lane = tid & 63, wave = tid >> 6;
    const int wm = wave >> 2, wn = wave & 3;
    const int fr = lane & 15, ks = lane >> 4;
    const int ksz = (ks ^ ((fr >> 1) & 3)) << 4;
    const int kq  = ((tid & 3) ^ ((tid >> 3) & 3)) * 8;
    const int srow = tid >> 2;   // [0,128)

    const long a_off0 = (row0 + srow) * D_DIM + kq;
    const long a_off1 = (row0 + 128 + srow) * D_DIM + kq;
    const long b_off0 = (long)(col0 + srow) * D_DIM + kq;
    const long b_off1 = (long)(col0 + 128 + srow) * D_DIM + kq;

    f32x4 acc[8][4] = {};

    // prologue
    gload16(A + a_off0, (char*)&As[0][0] + tid * 16);
    gload16(A + a_off1, (char*)&As[0][0] + 8192 + tid * 16);
    gload16(W + b_off0, (char*)&Bs[0][0] + tid * 16);
    gload16(W + b_off1, (char*)&Bs[0][0] + 8192 + tid * 16);
    __syncthreads();

    int cur = 0;
    for (int t = 0; t < 32; ++t) {
        const int nxt = cur ^ 1;
        if (t < 31) {
            const int k0 = (t + 1) * 32;
            gload16(A + a_off0 + k0, (char*)&As[nxt][0] + tid * 16);
            gload16(A + a_off1 + k0, (char*)&As[nxt][0] + 8192 + tid * 16);
            gload16(W + b_off0 + k0, (char*)&Bs[nxt][0] + tid * 16);
            gload16(W + b_off1 + k0, (char*)&Bs[nxt][0] + 8192 + tid * 16);
        }

        short8 bfrag[4];
#pragma unroll
        for (int ni = 0; ni < 4; ++ni)
            bfrag[ni] = *(const short8*)((char*)&Bs[cur][0] + (wn * 64 + ni * 16 + fr) * 64 + ksz);
#pragma unroll
        for (int mi = 0; mi < 8; ++mi) {
            const short8 a = *(const short8*)((char*)&As[cur][0] + (wm * 128 + mi * 16 + fr) * 64 + ksz);
#pragma unroll
            for (int ni = 0; ni < 4; ++ni)
                acc[mi][ni] = __builtin_amdgcn_mfma_f32_16x16x32_bf16(a, bfrag[ni], acc[mi][ni], 0, 0, 0);
        }
        __syncthreads();
        cur = nxt;
    }

    const int c = lane & 15, rg = lane >> 4;
#pragma unroll
    for (int mi = 0; mi < 8; ++mi)
#pragma unroll
        for (int ni = 0; ni < 4; ++ni)
#pragma unroll
            for (int j = 0; j < 4; ++j) {
                const long row = row0 + wm * 128 + mi * 16 + rg * 4 + j;
                const int  col = col0 + wn * 64 + ni * 16 + c;
                C[row * D_DIM + col] = resid[row * D_DIM + col] + acc[mi][ni][j];
            }
}

// ---------------------------------------------------------------------------
extern "C" void kernel_launch(void* const* d_in, const int* in_sizes, int n_in,
                              void* d_out, int out_size, void* d_ws, size_t ws_size,
                              hipStream_t stream)
{
    const float* x    = (const float*)d_in[0];
    const float* ctx  = (const float*)d_in[1];
    const int*   cidx = (const int*)d_in[2];
    const float* gq   = (const float*)d_in[3];
    const float* gkv  = (const float*)d_in[4];
    const float* Wq   = (const float*)d_in[5];
    const float* Wk   = (const float*)d_in[6];
    const float* Wv   = (const float*)d_in[7];
    const float* Wo   = (const float*)d_in[8];
    float* out = (float*)d_out;

    char* ws = (char*)d_ws;
    const size_t MB = 1 << 20;
    unsigned short* wq_hi = (unsigned short*)(ws + 0 * MB);
    unsigned short* wq_lo = (unsigned short*)(ws + 2 * MB);
    unsigned short* wk_hi = (unsigned short*)(ws + 4 * MB);
    unsigned short* wk_lo = (unsigned short*)(ws + 6 * MB);
    unsigned short* wv_hi = (unsigned short*)(ws + 8 * MB);
    unsigned short* wv_lo = (unsigned short*)(ws + 10 * MB);
    unsigned short* wo_b  = (unsigned short*)(ws + 12 * MB);
    unsigned short* xh = (unsigned short*)(ws + 14 * MB);   // 32MB
    unsigned short* xl = (unsigned short*)(ws + 46 * MB);   // 32MB
    unsigned short* ch = (unsigned short*)(ws + 78 * MB);   // 2MB
    unsigned short* cl = (unsigned short*)(ws + 80 * MB);   // 2MB
    float* k_f = (float*)(ws + 82 * MB);                    // 4MB
    float* v_f = (float*)(ws + 86 * MB);                    // 4MB
    unsigned short* ao_b = (unsigned short*)(ws + 90 * MB); // 32MB; total 122MB

    // 1. fold gamma into Wq/Wk/Wv, split hi/lo; Wo -> bf16
    convw_kernel<<<4096, 256, 0, stream>>>(Wq, Wk, Wv, Wo, gq, gkv, ws);
    // 2. rmsnorm + split (x and ctx)
    rms_split_kernel<<<16384, 256, 0, stream>>>(x, xh, xl);
    rms_split_kernel<<<1024, 256, 0, stream>>>(ctx, ch, cl);
    // 3. k,v (split precision, f32 out)
    gemm_kv<<<dim3(8, 8, 2), 256, 0, stream>>>(ch, cl, wk_hi, wk_lo, wv_hi, wv_lo,
                                               k_f, v_f);
    // 4. fused q projection + band attention -> ao (bf16)
    qattn3_kernel<<<512, 512, 0, stream>>>(xh, xl, wq_hi, wq_lo, k_f, v_f,
                                           cidx, ao_b);
    // 5. out = x + ao @ Wo^T
    gemm_out256<<<256, 512, 0, stream>>>(ao_b, wo_b, out, x);
}

// Round 6
// 242.240 us; speedup vs baseline: 1.5121x; 1.5121x over previous
//
#include <hip/hip_runtime.h>
#include <hip/hip_bf16.h>
#include <stdint.h>

// B=4, T=4096, K=256, D=1024, H=16, hd=64
#define D_DIM 1024

using f32x4  = __attribute__((ext_vector_type(4))) float;
using short8 = __attribute__((ext_vector_type(8))) short;

__device__ __forceinline__ float bf2f(unsigned short u) {
    union { unsigned int i; float f; } v; v.i = ((unsigned int)u) << 16; return v.f;
}
__device__ __forceinline__ unsigned short f2bf(float f) {
    union { float f; unsigned int i; } v; v.f = f;
    unsigned int x = v.i;
    return (unsigned short)((x + 0x7fffu + ((x >> 16) & 1u)) >> 16);  // RNE
}
__device__ __forceinline__ void gload16(const void* g, void* l) {
    __builtin_amdgcn_global_load_lds(
        (const __attribute__((address_space(1))) void*)g,
        (__attribute__((address_space(3))) void*)l, 16, 0, 0);
}

// LDS tile layout: [row][32 bf16] = 64B rows, 4 x 16B slots/row.
// T2 swizzle (rule #21 both-sides): LDS dest linear; global source k-seg and
// the ds_read slot both XOR (row>>1)&3. Verified round 5: conflicts 6.3M -> 0.

// ---------------------------------------------------------------------------
// Weight fold+split: W' = gamma ⊙ W, split f32 -> hi+lo bf16.
// sel 0..2 (Wq,Wk,Wv): hi at ws+sel*4MB, lo at +2MB.  sel 3 (Wo): bf16 @12MB.
// ---------------------------------------------------------------------------
__global__ __launch_bounds__(256)
void convw_kernel(const float* __restrict__ Wq, const float* __restrict__ Wk,
                  const float* __restrict__ Wv, const float* __restrict__ Wo,
                  const float* __restrict__ gq, const float* __restrict__ gkv,
                  char* __restrict__ ws)
{
    const int e   = (blockIdx.x * 256 + threadIdx.x) * 4;
    const int sel = e >> 20;
    const int off = e & 0xFFFFF;
    const float* src = sel == 0 ? Wq : sel == 1 ? Wk : sel == 2 ? Wv : Wo;
    float4 v = *(const float4*)(src + off);
    if (sel < 3) {
        const float* gam = (sel == 0) ? gq : gkv;
        float4 g = *(const float4*)(gam + (off & 1023));
        v.x *= g.x; v.y *= g.y; v.z *= g.z; v.w *= g.w;
        ushort4 h, l;
        h.x = f2bf(v.x); l.x = f2bf(v.x - bf2f(h.x));
        h.y = f2bf(v.y); l.y = f2bf(v.y - bf2f(h.y));
        h.z = f2bf(v.z); l.z = f2bf(v.z - bf2f(h.z));
        h.w = f2bf(v.w); l.w = f2bf(v.w - bf2f(h.w));
        unsigned short* hi = (unsigned short*)(ws + (size_t)sel * (4u << 20));
        unsigned short* lo = (unsigned short*)(ws + (size_t)sel * (4u << 20) + (2u << 20));
        *(ushort4*)(hi + off) = h;
        *(ushort4*)(lo + off) = l;
    } else {
        ushort4 o;
        o.x = f2bf(v.x); o.y = f2bf(v.y); o.z = f2bf(v.z); o.w = f2bf(v.w);
        *(ushort4*)((unsigned short*)(ws + (12u << 20)) + off) = o;
    }
}

// ---------------------------------------------------------------------------
// RMSNorm + split: xh = bf16(x*scale), xl = bf16(x*scale - xh). One block/row.
// ---------------------------------------------------------------------------
__global__ __launch_bounds__(256)
void rms_split_kernel(const float* __restrict__ x,
                      unsigned short* __restrict__ xh, unsigned short* __restrict__ xl)
{
    const long row = blockIdx.x;
    float4 v = ((const float4*)(x + row * D_DIM))[threadIdx.x];
    float ss = v.x*v.x + v.y*v.y + v.z*v.z + v.w*v.w;
#pragma unroll
    for (int m = 32; m; m >>= 1) ss += __shfl_xor(ss, m);
    __shared__ float red[4];
    if ((threadIdx.x & 63) == 0) red[threadIdx.x >> 6] = ss;
    __syncthreads();
    const float tot = red[0] + red[1] + red[2] + red[3];
    const float scale = rsqrtf(tot * (1.0f / 1024.0f) + 1.1920929e-07f);
    v.x *= scale; v.y *= scale; v.z *= scale; v.w *= scale;
    ushort4 h, l;
    h.x = f2bf(v.x); l.x = f2bf(v.x - bf2f(h.x));
    h.y = f2bf(v.y); l.y = f2bf(v.y - bf2f(h.y));
    h.z = f2bf(v.z); l.z = f2bf(v.z - bf2f(h.z));
    h.w = f2bf(v.w); l.w = f2bf(v.w - bf2f(h.w));
    *(ushort4*)(xh + row * D_DIM + threadIdx.x * 4) = h;
    *(ushort4*)(xl + row * D_DIM + threadIdx.x * 4) = l;
}

// ---------------------------------------------------------------------------
// kv GEMM: O = (ch+cl) @ (Bhi+Blo)^T, 128x128 tile, swizzled. (validated r5)
// ---------------------------------------------------------------------------
__global__ __launch_bounds__(256)
void gemm_kv(const unsigned short* __restrict__ ch, const unsigned short* __restrict__ cl,
             const unsigned short* __restrict__ Bh0, const unsigned short* __restrict__ Bl0,
             const unsigned short* __restrict__ Bh1, const unsigned short* __restrict__ Bl1,
             float* __restrict__ O0, float* __restrict__ O1)
{
    __shared__ unsigned short Ah[4096], Al[4096], Bh[4096], Bl[4096];
    const unsigned short* Bhp = blockIdx.z ? Bh1 : Bh0;
    const unsigned short* Blp = blockIdx.z ? Bl1 : Bl0;
    float* O = blockIdx.z ? O1 : O0;

    const int tid = threadIdx.x, lane = tid & 63, wave = tid >> 6;
    const int wm = wave >> 1, wn = wave & 1;
    const long Arow0 = (long)blockIdx.y * 128;
    const int  Brow0 = blockIdx.x * 128;
    const int fr = lane & 15, ks = lane >> 4;
    const int ksz = (ks ^ ((fr >> 1) & 3)) << 4;
    const int kq  = ((tid & 3) ^ ((tid >> 3) & 3)) * 8;
    const int srow = tid >> 2;

    const long a_off0 = (Arow0 + srow) * D_DIM + kq;
    const long a_off1 = (Arow0 + srow + 64) * D_DIM + kq;
    const long b_off0 = (long)(Brow0 + srow) * D_DIM + kq;
    const long b_off1 = (long)(Brow0 + srow + 64) * D_DIM + kq;

    f32x4 acc[4][4] = {};
    char* AhB = (char*)Ah; char* AlB = (char*)Al;
    char* BhB = (char*)Bh; char* BlB = (char*)Bl;

    for (int kt = 0; kt < 32; ++kt) {
        const int k0 = kt * 32;
        gload16(ch + a_off0 + k0, AhB + tid * 16);
        gload16(ch + a_off1 + k0, AhB + 4096 + tid * 16);
        gload16(cl + a_off0 + k0, AlB + tid * 16);
        gload16(cl + a_off1 + k0, AlB + 4096 + tid * 16);
        gload16(Bhp + b_off0 + k0, BhB + tid * 16);
        gload16(Bhp + b_off1 + k0, BhB + 4096 + tid * 16);
        gload16(Blp + b_off0 + k0, BlB + tid * 16);
        gload16(Blp + b_off1 + k0, BlB + 4096 + tid * 16);
        __syncthreads();

        short8 ah[4], al[4], bh[4], bl[4];
#pragma unroll
        for (int mi = 0; mi < 4; ++mi) {
            const int aoff = (wm * 64 + mi * 16 + fr) * 64 + ksz;
            ah[mi] = *(const short8*)(AhB + aoff);
            al[mi] = *(const short8*)(AlB + aoff);
        }
#pragma unroll
        for (int ni = 0; ni < 4; ++ni) {
            const int boff = (wn * 64 + ni * 16 + fr) * 64 + ksz;
            bh[ni] = *(const short8*)(BhB + boff);
            bl[ni] = *(const short8*)(BlB + boff);
        }
#pragma unroll
        for (int mi = 0; mi < 4; ++mi)
#pragma unroll
            for (int ni = 0; ni < 4; ++ni) {
                acc[mi][ni] = __builtin_amdgcn_mfma_f32_16x16x32_bf16(ah[mi], bh[ni], acc[mi][ni], 0, 0, 0);
                acc[mi][ni] = __builtin_amdgcn_mfma_f32_16x16x32_bf16(al[mi], bh[ni], acc[mi][ni], 0, 0, 0);
                acc[mi][ni] = __builtin_amdgcn_mfma_f32_16x16x32_bf16(ah[mi], bl[ni], acc[mi][ni], 0, 0, 0);
            }
        __syncthreads();
    }

    const int c = lane & 15, r0 = (lane >> 4) * 4;
#pragma unroll
    for (int mi = 0; mi < 4; ++mi)
#pragma unroll
        for (int ni = 0; ni < 4; ++ni)
#pragma unroll
            for (int j = 0; j < 4; ++j) {
                const long row = Arow0 + wm * 64 + mi * 16 + r0 + j;
                const int  col = Brow0 + wn * 64 + ni * 16 + c;
                O[row * D_DIM + col] = acc[mi][ni][j];
            }
}

// ---------------------------------------------------------------------------
// FUSED q-projection + band attention. BM=256 x BN=256 (4 heads), grid 256,
// round-4 double-buffered skeleton + swizzle + pre-split pure-gload16 staging.
// LDS: (Ah,Al,Bh,Bl) x 2 x 16KB = 128KB -> 1 block/CU. VGPR target 128 (r4).
// ---------------------------------------------------------------------------
__global__ __launch_bounds__(512, 2)
void qattn4_kernel(const unsigned short* __restrict__ xh, const unsigned short* __restrict__ xl,
                   const unsigned short* __restrict__ Wh, const unsigned short* __restrict__ Wl,
                   const float* __restrict__ kf, const float* __restrict__ vf,
                   const int* __restrict__ cidx, unsigned short* __restrict__ ao)
{
    __shared__ unsigned short Ah[2][8192], Al[2][8192];
    __shared__ unsigned short Bh[2][8192], Bl[2][8192];

    const int lin = blockIdx.x;
    const int bx = (lin >> 3) & 3;
    const int by = ((lin >> 5) << 3) | (lin & 7);
    const int row0 = by * 256;
    const int col0 = bx * 256;
    const int b = row0 >> 12;

    const int tid = threadIdx.x, lane = tid & 63, wave = tid >> 6;
    const int wm = wave >> 2, wn = wave & 3;
    const int fr = lane & 15, ks = lane >> 4;
    const int ksz = (ks ^ ((fr >> 1) & 3)) << 4;
    const int kq  = ((tid & 3) ^ ((tid >> 3) & 3)) * 8;
    const int srow = tid >> 2;   // [0,128)

    const long a_off0 = (long)(row0 + srow) * D_DIM + kq;
    const long a_off1 = (long)(row0 + 128 + srow) * D_DIM + kq;
    const long w_off0 = (long)(col0 + srow) * D_DIM + kq;
    const long w_off1 = (long)(col0 + 128 + srow) * D_DIM + kq;

    f32x4 acc[8][4] = {};

    // prologue: stage tile 0 into buf 0
    gload16(xh + a_off0, (char*)&Ah[0][0] + tid * 16);
    gload16(xh + a_off1, (char*)&Ah[0][0] + 8192 + tid * 16);
    gload16(xl + a_off0, (char*)&Al[0][0] + tid * 16);
    gload16(xl + a_off1, (char*)&Al[0][0] + 8192 + tid * 16);
    gload16(Wh + w_off0, (char*)&Bh[0][0] + tid * 16);
    gload16(Wh + w_off1, (char*)&Bh[0][0] + 8192 + tid * 16);
    gload16(Wl + w_off0, (char*)&Bl[0][0] + tid * 16);
    gload16(Wl + w_off1, (char*)&Bl[0][0] + 8192 + tid * 16);
    __syncthreads();

    int cur = 0;
    for (int t = 0; t < 32; ++t) {
        const int nxt = cur ^ 1;
        if (t < 31) {
            const int k0 = (t + 1) * 32;
            gload16(xh + a_off0 + k0, (char*)&Ah[nxt][0] + tid * 16);
            gload16(xh + a_off1 + k0, (char*)&Ah[nxt][0] + 8192 + tid * 16);
            gload16(xl + a_off0 + k0, (char*)&Al[nxt][0] + tid * 16);
            gload16(xl + a_off1 + k0, (char*)&Al[nxt][0] + 8192 + tid * 16);
            gload16(Wh + w_off0 + k0, (char*)&Bh[nxt][0] + tid * 16);
            gload16(Wh + w_off1 + k0, (char*)&Bh[nxt][0] + 8192 + tid * 16);
            gload16(Wl + w_off0 + k0, (char*)&Bl[nxt][0] + tid * 16);
            gload16(Wl + w_off1 + k0, (char*)&Bl[nxt][0] + 8192 + tid * 16);
        }

        short8 bh[4], bl[4];
#pragma unroll
        for (int ni = 0; ni < 4; ++ni) {
            const int boff = (wn * 64 + ni * 16 + fr) * 64 + ksz;
            bh[ni] = *(const short8*)((char*)&Bh[cur][0] + boff);
            bl[ni] = *(const short8*)((char*)&Bl[cur][0] + boff);
        }
#pragma unroll
        for (int mi = 0; mi < 8; ++mi) {
            const int aoff = (wm * 128 + mi * 16 + fr) * 64 + ksz;
            const short8 ah = *(const short8*)((char*)&Ah[cur][0] + aoff);
            const short8 al = *(const short8*)((char*)&Al[cur][0] + aoff);
#pragma unroll
            for (int ni = 0; ni < 4; ++ni) {
                acc[mi][ni] = __builtin_amdgcn_mfma_f32_16x16x32_bf16(ah, bh[ni], acc[mi][ni], 0, 0, 0);
                acc[mi][ni] = __builtin_amdgcn_mfma_f32_16x16x32_bf16(al, bh[ni], acc[mi][ni], 0, 0, 0);
                acc[mi][ni] = __builtin_amdgcn_mfma_f32_16x16x32_bf16(ah, bl[ni], acc[mi][ni], 0, 0, 0);
            }
        }
        __syncthreads();
        cur = nxt;
    }

    // ---- in-register band attention (wave owns head bx*4+wn) ----
    const int c = lane & 15, rg = lane >> 4;
    const int hcol = col0 + wn * 64;
    const float* kb = kf + (long)b * 256 * D_DIM + hcol + c;
    const float* vb = vf + (long)b * 256 * D_DIM + hcol + c;
#pragma unroll
    for (int mi = 0; mi < 8; ++mi) {
        float wgt[4][3];
        int   pos[4][3];
#pragma unroll
        for (int j = 0; j < 4; ++j) {
            const int tok = row0 + wm * 128 + mi * 16 + rg * 4 + j;
            const int idx = cidx[tok];
            float wsum = 0.f;
#pragma unroll
            for (int dp = 0; dp < 3; ++dp) {
                const int p = idx + dp - 1;
                const bool valid = (p >= 0) && (p < 256);
                const int pc = valid ? p : 0;
                const float* kr = kb + (long)pc * D_DIM;
                float dot = acc[mi][0][j] * kr[0]  + acc[mi][1][j] * kr[16]
                          + acc[mi][2][j] * kr[32] + acc[mi][3][j] * kr[48];
                dot += __shfl_xor(dot, 1);
                dot += __shfl_xor(dot, 2);
                dot += __shfl_xor(dot, 4);
                dot += __shfl_xor(dot, 8);
                const float s = dot * 0.125f;
                const float w = (valid && s > 0.f) ? s * s : 0.f;
                wsum += w; wgt[j][dp] = w; pos[j][dp] = pc;
            }
            const float inv = 1.0f / fmaxf(wsum, 1e-6f);
            wgt[j][0] *= inv; wgt[j][1] *= inv; wgt[j][2] *= inv;
        }
#pragma unroll
        for (int ni = 0; ni < 4; ++ni)
#pragma unroll
            for (int j = 0; j < 4; ++j) {
                float a = 0.f;
#pragma unroll
                for (int dp = 0; dp < 3; ++dp)
                    a += wgt[j][dp] * vb[(long)pos[j][dp] * D_DIM + ni * 16];
                acc[mi][ni][j] = a;
            }
    }

#pragma unroll
    for (int mi = 0; mi < 8; ++mi)
#pragma unroll
        for (int ni = 0; ni < 4; ++ni)
#pragma unroll
            for (int j = 0; j < 4; ++j) {
                const long tok = row0 + wm * 128 + mi * 16 + rg * 4 + j;
                ao[tok * D_DIM + hcol + ni * 16 + c] = f2bf(acc[mi][ni][j]);
            }
}

// ---------------------------------------------------------------------------
// out = x + ao @ Wo^T, 256x256, double-buffered, swizzled. grid 256.
// ---------------------------------------------------------------------------
__global__ __launch_bounds__(512, 2)
void gemm_out256(const unsigned short* __restrict__ A,
                 const unsigned short* __restrict__ W,
                 float* __restrict__ C, const float* __restrict__ resid)
{
    __shared__ unsigned short As[2][8192];
    __shared__ unsigned short Bs[2][8192];

    const int lin = blockIdx.x;
    const int bx = (lin >> 3) & 3;
    const int by = ((lin >> 5) << 3) | (lin & 7);
    const long row0 = (long)by * 256;
    const int  col0 = bx * 256;

    const int tid = threadIdx.x, lane = tid & 63, wave = tid >> 6;
    const int wm = wave >> 2, wn = wave & 3;
    const int fr = lane & 15, ks = lane >> 4;
    const int ksz = (ks ^ ((fr >> 1) & 3)) << 4;
    const int kq  = ((tid & 3) ^ ((tid >> 3) & 3)) * 8;
    const int srow = tid >> 2;

    const long a_off0 = (row0 + srow) * D_DIM + kq;
    const long a_off1 = (row0 + 128 + srow) * D_DIM + kq;
    const long b_off0 = (long)(col0 + srow) * D_DIM + kq;
    const long b_off1 = (long)(col0 + 128 + srow) * D_DIM + kq;

    f32x4 acc[8][4] = {};

    gload16(A + a_off0, (char*)&As[0][0] + tid * 16);
    gload16(A + a_off1, (char*)&As[0][0] + 8192 + tid * 16);
    gload16(W + b_off0, (char*)&Bs[0][0] + tid * 16);
    gload16(W + b_off1, (char*)&Bs[0][0] + 8192 + tid * 16);
    __syncthreads();

    int cur = 0;
    for (int t = 0; t < 32; ++t) {
        const int nxt = cur ^ 1;
        if (t < 31) {
            const int k0 = (t + 1) * 32;
            gload16(A + a_off0 + k0, (char*)&As[nxt][0] + tid * 16);
            gload16(A + a_off1 + k0, (char*)&As[nxt][0] + 8192 + tid * 16);
            gload16(W + b_off0 + k0, (char*)&Bs[nxt][0] + tid * 16);
            gload16(W + b_off1 + k0, (char*)&Bs[nxt][0] + 8192 + tid * 16);
        }

        short8 bfrag[4];
#pragma unroll
        for (int ni = 0; ni < 4; ++ni)
            bfrag[ni] = *(const short8*)((char*)&Bs[cur][0] + (wn * 64 + ni * 16 + fr) * 64 + ksz);
#pragma unroll
        for (int mi = 0; mi < 8; ++mi) {
            const short8 a = *(const short8*)((char*)&As[cur][0] + (wm * 128 + mi * 16 + fr) * 64 + ksz);
#pragma unroll
            for (int ni = 0; ni < 4; ++ni)
                acc[mi][ni] = __builtin_amdgcn_mfma_f32_16x16x32_bf16(a, bfrag[ni], acc[mi][ni], 0, 0, 0);
        }
        __syncthreads();
        cur = nxt;
    }

    const int c = lane & 15, rg = lane >> 4;
#pragma unroll
    for (int mi = 0; mi < 8; ++mi)
#pragma unroll
        for (int ni = 0; ni < 4; ++ni)
#pragma unroll
            for (int j = 0; j < 4; ++j) {
                const long row = row0 + wm * 128 + mi * 16 + rg * 4 + j;
                const int  col = col0 + wn * 64 + ni * 16 + c;
                C[row * D_DIM + col] = resid[row * D_DIM + col] + acc[mi][ni][j];
            }
}

// ---------------------------------------------------------------------------
extern "C" void kernel_launch(void* const* d_in, const int* in_sizes, int n_in,
                              void* d_out, int out_size, void* d_ws, size_t ws_size,
                              hipStream_t stream)
{
    const float* x    = (const float*)d_in[0];
    const float* ctx  = (const float*)d_in[1];
    const int*   cidx = (const int*)d_in[2];
    const float* gq   = (const float*)d_in[3];
    const float* gkv  = (const float*)d_in[4];
    const float* Wq   = (const float*)d_in[5];
    const float* Wk   = (const float*)d_in[6];
    const float* Wv   = (const float*)d_in[7];
    const float* Wo   = (const float*)d_in[8];
    float* out = (float*)d_out;

    char* ws = (char*)d_ws;
    const size_t MB = 1 << 20;
    unsigned short* wq_hi = (unsigned short*)(ws + 0 * MB);
    unsigned short* wq_lo = (unsigned short*)(ws + 2 * MB);
    unsigned short* wk_hi = (unsigned short*)(ws + 4 * MB);
    unsigned short* wk_lo = (unsigned short*)(ws + 6 * MB);
    unsigned short* wv_hi = (unsigned short*)(ws + 8 * MB);
    unsigned short* wv_lo = (unsigned short*)(ws + 10 * MB);
    unsigned short* wo_b  = (unsigned short*)(ws + 12 * MB);
    unsigned short* xh = (unsigned short*)(ws + 14 * MB);   // 32MB
    unsigned short* xl = (unsigned short*)(ws + 46 * MB);   // 32MB
    unsigned short* ch = (unsigned short*)(ws + 78 * MB);   // 2MB
    unsigned short* cl = (unsigned short*)(ws + 80 * MB);   // 2MB
    float* k_f = (float*)(ws + 82 * MB);                    // 4MB
    float* v_f = (float*)(ws + 86 * MB);                    // 4MB
    unsigned short* ao_b = (unsigned short*)(ws + 90 * MB); // 32MB; total 122MB

    // 1. fold gamma into Wq/Wk/Wv, split hi/lo; Wo -> bf16
    convw_kernel<<<4096, 256, 0, stream>>>(Wq, Wk, Wv, Wo, gq, gkv, ws);
    // 2. rmsnorm + split (x and ctx)
    rms_split_kernel<<<16384, 256, 0, stream>>>(x, xh, xl);
    rms_split_kernel<<<1024, 256, 0, stream>>>(ctx, ch, cl);
    // 3. k,v (split precision, f32 out)
    gemm_kv<<<dim3(8, 8, 2), 256, 0, stream>>>(ch, cl, wk_hi, wk_lo, wv_hi, wv_lo,
                                               k_f, v_f);
    // 4. fused q projection + band attention -> ao (bf16)
    qattn4_kernel<<<256, 512, 0, stream>>>(xh, xl, wq_hi, wq_lo, k_f, v_f,
                                           cidx, ao_b);
    // 5. out = x + ao @ Wo^T
    gemm_out256<<<256, 512, 0, stream>>>(ao_b, wo_b, out, x);
}